// Round 2
// baseline (408.428 us; speedup 1.0000x reference)
//
#include <hip/hip_runtime.h>
#include <hip/hip_bf16.h>
#include <math.h>

// Problem constants (from reference)
#define PTOK 4096      // P
#define BDIM 4         // B
#define FULLD 4096     // FULL
#define SLICE 512
#define SL_START 1024
#define EDIM 1024
#define FP_MIN_C 0.1875f
#define FP_MAX_C 0.4375f

typedef __attribute__((ext_vector_type(8))) short bf16x8;
typedef __attribute__((ext_vector_type(4))) float f32x4;

// round-to-nearest-even f32 -> bf16 bits
__device__ __forceinline__ unsigned short f2bf(float f) {
    unsigned int u = __float_as_uint(f);
    unsigned int r = (u + 0x7fffu + ((u >> 16) & 1u)) >> 16;
    return (unsigned short)r;
}

__device__ __forceinline__ void gl2lds16(const void* g, void* l) {
    __builtin_amdgcn_global_load_lds(
        (const __attribute__((address_space(1))) unsigned int*)g,
        (__attribute__((address_space(3))) unsigned int*)(unsigned long long)(uintptr_t)l,
        16, 0, 0);
}

// ---------------------------------------------------------------------------
// 1) fused prep: block 0 = fingerprint scan; blocks 1..384 = weight fp32->bf16
//    convert; blocks 385..390 = Wproj[z,v,k] = sum_d W_z[d,k] * dir_v[d]
//    (each Wproj block renormalizes penta itself -> no intra-kernel dep)
// ---------------------------------------------------------------------------
__global__ __launch_bounds__(1024) void prep_kernel(const float* __restrict__ fp,
                                                    int* __restrict__ idx,
                                                    const float* __restrict__ penta,
                                                    const float* __restrict__ Wq,
                                                    const float* __restrict__ Wk,
                                                    const float* __restrict__ Wv,
                                                    unsigned short* __restrict__ Wb,
                                                    float* __restrict__ wproj) {
    int blk = blockIdx.x;
    int t = threadIdx.x;
    if (blk == 0) {
        // shuffle-based scan over 4096 fingerprints (4/thread)
        int m[4];
        int c = 0;
#pragma unroll
        for (int i = 0; i < 4; ++i) {
            float f = fp[t * 4 + i];
            m[i] = (f >= FP_MIN_C && f < FP_MAX_C) ? 1 : 0;
            c += m[i];
        }
        int lane = t & 63, wv = t >> 6;
        int inc = c;
#pragma unroll
        for (int off = 1; off < 64; off <<= 1) {
            int n = __shfl_up(inc, off, 64);
            if (lane >= off) inc += n;
        }
        __shared__ int wsum[16];
        if (lane == 63) wsum[wv] = inc;
        __syncthreads();
        if (t < 16) {
            int v = wsum[t];
            int in2 = v;
#pragma unroll
            for (int off = 1; off < 16; off <<= 1) {
                int n = __shfl_up(in2, off, 16);
                if (t >= off) in2 += n;
            }
            wsum[t] = in2 - v;  // exclusive wave base
        }
        __syncthreads();
        int pos = wsum[wv] + inc - c;
#pragma unroll
        for (int i = 0; i < 4; ++i) {
            if (m[i]) idx[pos++] = t * 4 + i;
        }
    } else if (blk <= 384) {
        int i = (blk - 1) * 1024 + t;  // float4 index over 3*131072
        int mat = i >> 17;
        int rem = i & 131071;
        const float* src = (mat == 0) ? Wq : ((mat == 1) ? Wk : Wv);
        float4 v = ((const float4*)src)[rem];
        ushort4 o;
        o.x = f2bf(v.x); o.y = f2bf(v.y); o.z = f2bf(v.z); o.w = f2bf(v.w);
        ((ushort4*)(Wb + (size_t)mat * EDIM * SLICE))[rem] = o;
    } else {
        // Wproj: block handles matrix zz, 256-column half kh.
        int zz = (blk - 385) >> 1;
        int kh = (blk - 385) & 1;
        __shared__ float dl[5 * EDIM + 8];  // penta rows, then reused as partials
        for (int i = t; i < 5 * EDIM; i += 1024) dl[i] = penta[i];
        __syncthreads();
        if (t < 320) {  // 5 waves: inverse norms
            int v = t >> 6, l = t & 63;
            float ss = 0.f;
            for (int i = l; i < EDIM; i += 64) {
                float x = dl[v * EDIM + i];
                ss += x * x;
            }
            for (int off = 32; off > 0; off >>= 1) ss += __shfl_down(ss, off, 64);
            if (l == 0) dl[5 * EDIM + v] = 1.0f / sqrtf(ss);
        }
        __syncthreads();
        int kk = t & 255;       // column within half
        int dq = t >> 8;        // d-quarter 0..3
        int k = kh * 256 + kk;
        const float* Wz = (zz == 0) ? Wq : ((zz == 1) ? Wk : Wv);
        float inv[5];
#pragma unroll
        for (int v = 0; v < 5; ++v) inv[v] = dl[5 * EDIM + v];
        float acc[5] = {0.f, 0.f, 0.f, 0.f, 0.f};
#pragma unroll 4
        for (int d0 = 0; d0 < 256; ++d0) {
            int d = dq * 256 + d0;
            float w = Wz[(size_t)d * SLICE + k];
#pragma unroll
            for (int v = 0; v < 5; ++v) acc[v] += w * dl[v * EDIM + d];
        }
        __syncthreads();  // done reading dirs region
#pragma unroll
        for (int v = 0; v < 5; ++v) dl[(dq * 5 + v) * 256 + kk] = acc[v] * inv[v];
        __syncthreads();
        if (t < 256) {
#pragma unroll
            for (int v = 0; v < 5; ++v) {
                float s = dl[(0 + v) * 256 + t] + dl[(5 + v) * 256 + t]
                        + dl[(10 + v) * 256 + t] + dl[(15 + v) * 256 + t];
                wproj[((size_t)zz * 5 + v) * SLICE + kh * 256 + t] = s;
            }
        }
    }
}

// ---------------------------------------------------------------------------
// 2) gather + gating MLP + scale -> Ag (M x 512, bf16); 8 tokens per block
// ---------------------------------------------------------------------------
#define GT 8
__global__ __launch_bounds__(256) void gate_kernel(const float* __restrict__ tokens,
                                                   const int* __restrict__ idx,
                                                   const float* __restrict__ Wg1,
                                                   const float* __restrict__ bg1,
                                                   const float* __restrict__ Wg2,
                                                   const float* __restrict__ bg2,
                                                   const float* __restrict__ alpha,
                                                   unsigned short* __restrict__ Ag,
                                                   int Ntok, int M) {
    __shared__ float rows[GT][SLICE];   // 16 KB
    __shared__ float hred[GT][128];     // 4 KB
    __shared__ float ssc[GT];

    int tid = threadIdx.x;
    int tok0 = blockIdx.x * GT;

    // stage 8 token rows (coalesced within each half-row)
#pragma unroll
    for (int i = 0; i < 4; ++i) {
        int flat = i * 256 + tid;           // float4 slot
        int tk = flat >> 7, c4 = flat & 127;
        int g = tok0 + tk;
        if (g >= M) g = M - 1;
        int b = g / Ntok;
        int j = g - b * Ntok;
        int p = idx[j];
        const float4* src = (const float4*)(tokens + ((size_t)b * PTOK + p) * FULLD + SL_START);
        ((float4*)rows[tk])[c4] = src[c4];
    }
    __syncthreads();

    int hidx = tid & 127;
    int grp = tid >> 7;  // tokens grp*4 .. grp*4+3
    const float4* w4 = (const float4*)(Wg1 + (size_t)hidx * SLICE);
    float bias = bg1[hidx];
    float acc[4] = {bias, bias, bias, bias};
#pragma unroll 4
    for (int k = 0; k < SLICE / 4; ++k) {
        float4 w = w4[k];
#pragma unroll
        for (int t8 = 0; t8 < 4; ++t8) {
            float4 r = ((const float4*)rows[grp * 4 + t8])[k];
            acc[t8] += r.x * w.x + r.y * w.y + r.z * w.z + r.w * w.w;
        }
    }
    float wg2 = Wg2[hidx];
#pragma unroll
    for (int t8 = 0; t8 < 4; ++t8) {
        float a = acc[t8];
        float hg = 0.5f * a * (1.0f + erff(a * 0.70710678118654752f));
        hred[grp * 4 + t8][hidx] = hg * wg2;
    }
    __syncthreads();

    int wv = tid >> 6, l = tid & 63;
    float aw = 1.0f / (1.0f + expf(-alpha[0]));
#pragma unroll
    for (int z = 0; z < 2; ++z) {
        int tk = wv * 2 + z;
        float v = hred[tk][l] + hred[tk][l + 64];
        for (int off = 32; off > 0; off >>= 1) v += __shfl_down(v, off, 64);
        if (l == 0) {
            float logit = v + bg2[0];
            float gate = 1.0f / (1.0f + expf(-logit));
            ssc[tk] = gate * aw + (1.0f - aw);
        }
    }
    __syncthreads();

#pragma unroll
    for (int i = 0; i < 4; ++i) {
        int flat = i * 256 + tid;
        int tk = flat >> 7, c4 = flat & 127;
        int g = tok0 + tk;
        if (g < M) {
            float4 r = ((const float4*)rows[tk])[c4];
            float s = ssc[tk];
            ushort4 o;
            o.x = f2bf(r.x * s); o.y = f2bf(r.y * s);
            o.z = f2bf(r.z * s); o.w = f2bf(r.w * s);
            ((ushort4*)(Ag + (size_t)g * SLICE))[c4] = o;
        }
    }
}

// ---------------------------------------------------------------------------
// 3) MFMA bf16 GEMM: C[m,n] = sum_k A[m,k] * W[n,k]
//    128x128 tile, BK=64 as two 32-col panels (keeps global_load_lds lane
//    contiguity AND conflict-free 32-col ds_read layout), 16 barriers total.
//    (reverted to round-0 form: fused proj epilogue cost more than it saved)
// ---------------------------------------------------------------------------
__global__ __launch_bounds__(256) void qkv_mfma(const unsigned short* __restrict__ Ag,
                                                const unsigned short* __restrict__ Wb,
                                                float* __restrict__ out, int M) {
    __shared__ short As[2][128 * 32];
    __shared__ short Bs[2][128 * 32];

    const unsigned short* W = Wb + (size_t)blockIdx.z * EDIM * SLICE;
    float* C = out + (size_t)blockIdx.z * M * EDIM;

    int tid = threadIdx.x;
    int bm = blockIdx.y * 128;
    int bn = blockIdx.x * 128;
    int l = tid & 63;
    int w = tid >> 6;
    int wr = w >> 1, wc = w & 1;  // 2x2 wave grid
    int lane16 = l & 15, kq = l >> 4;

    int srow = tid >> 2;
    int scol = (tid & 3) * 8;

    f32x4 acc[4][4] = {};

    for (int k0 = 0; k0 < SLICE; k0 += 64) {
#pragma unroll
        for (int p = 0; p < 2; ++p) {
#pragma unroll
            for (int r = 0; r < 2; ++r) {
                int arow = bm + r * 64 + srow;
                if (arow >= M) arow = M - 1;  // clamp (stores are guarded)
                gl2lds16(Ag + (size_t)arow * SLICE + k0 + p * 32 + scol,
                         &As[p][(r * 64 + srow) * 32 + scol]);
                int brow = bn + r * 64 + srow;
                gl2lds16(W + (size_t)brow * SLICE + k0 + p * 32 + scol,
                         &Bs[p][(r * 64 + srow) * 32 + scol]);
            }
        }
        __syncthreads();

#pragma unroll
        for (int p = 0; p < 2; ++p) {
            bf16x8 a[4], b[4];
#pragma unroll
            for (int i = 0; i < 4; ++i)
                a[i] = *(const bf16x8*)&As[p][(wr * 64 + i * 16 + lane16) * 32 + kq * 8];
#pragma unroll
            for (int j = 0; j < 4; ++j)
                b[j] = *(const bf16x8*)&Bs[p][(wc * 64 + j * 16 + lane16) * 32 + kq * 8];
#pragma unroll
            for (int i = 0; i < 4; ++i)
#pragma unroll
                for (int j = 0; j < 4; ++j)
                    acc[i][j] = __builtin_amdgcn_mfma_f32_16x16x32_bf16(a[i], b[j], acc[i][j], 0, 0, 0);
        }
        __syncthreads();
    }

    // D mapping: row m = (l>>4)*4 + reg, col n = l&15
#pragma unroll
    for (int i = 0; i < 4; ++i) {
        int m0 = bm + wr * 64 + i * 16 + kq * 4;
#pragma unroll
        for (int j = 0; j < 4; ++j) {
            int n = bn + wc * 64 + j * 16 + lane16;
            f32x4 v = acc[i][j];
#pragma unroll
            for (int r = 0; r < 4; ++r) {
                int m = m0 + r;
                if (m < M) C[(size_t)m * EDIM + n] = v[r];
            }
        }
    }
}

// ---------------------------------------------------------------------------
// 4) pentachoron projections via precomposed Wproj: reads Ag (4 MB bf16)
//    instead of Q/K/V (50 MB f32). Wave per token row, 15 outputs/row.
// ---------------------------------------------------------------------------
__global__ __launch_bounds__(256) void proj2_kernel(const unsigned short* __restrict__ Ag,
                                                    const float* __restrict__ wproj,
                                                    float* __restrict__ outp, int M) {
    int t = threadIdx.x;
    int m = blockIdx.x * 4 + (t >> 6);
    if (m >= M) return;
    int l = t & 63;

    // lane l holds a[8l..8l+7] of the scaled-gated row, as f32
    bf16x8 av = *(const bf16x8*)(Ag + (size_t)m * SLICE + (size_t)l * 8);
    float a[8];
#pragma unroll
    for (int i = 0; i < 8; ++i)
        a[i] = __uint_as_float(((unsigned int)(unsigned short)av[i]) << 16);

#pragma unroll
    for (int v = 0; v < 15; ++v) {
        const float4* wp4 = (const float4*)(wproj + (size_t)v * SLICE);
        float4 w0 = wp4[l * 2];
        float4 w1 = wp4[l * 2 + 1];
        float s = a[0] * w0.x + a[1] * w0.y + a[2] * w0.z + a[3] * w0.w
                + a[4] * w1.x + a[5] * w1.y + a[6] * w1.z + a[7] * w1.w;
#pragma unroll
        for (int off = 32; off > 0; off >>= 1) s += __shfl_down(s, off, 64);
        if (l == 0) outp[(size_t)v * M + m] = s;
    }
}

// ---------------------------------------------------------------------------
extern "C" void kernel_launch(void* const* d_in, const int* in_sizes, int n_in,
                              void* d_out, int out_size, void* d_ws, size_t ws_size,
                              hipStream_t stream) {
    const float* tokens = (const float*)d_in[0];
    const float* fp     = (const float*)d_in[1];
    const float* Wg1    = (const float*)d_in[2];
    const float* bg1    = (const float*)d_in[3];
    const float* Wg2    = (const float*)d_in[4];
    const float* bg2    = (const float*)d_in[5];
    const float* alpha  = (const float*)d_in[6];
    const float* Wq     = (const float*)d_in[7];
    const float* Wk     = (const float*)d_in[8];
    const float* Wv     = (const float*)d_in[9];
    const float* penta  = (const float*)d_in[10];
    float* out = (float*)d_out;

    int Ntok = out_size / 12348;
    int M = BDIM * Ntok;

    char* ws = (char*)d_ws;
    int*            idx   = (int*)ws;
    unsigned short* Ag    = (unsigned short*)(ws + (32 << 10));
    unsigned short* Wb    = (unsigned short*)(ws + (8 << 20));
    float*          wproj = (float*)(ws + (12 << 20));  // 15 x 512 f32

    float* outp = out + (size_t)3 * M * EDIM;  // projection region (15*M floats)

    prep_kernel<<<391, 1024, 0, stream>>>(fp, idx, penta, Wq, Wk, Wv, Wb, wproj);
    gate_kernel<<<(M + GT - 1) / GT, 256, 0, stream>>>(tokens, idx, Wg1, bg1, Wg2, bg2,
                                                       alpha, Ag, Ntok, M);

    dim3 gg(EDIM / 128, (M + 127) / 128, 3);
    qkv_mfma<<<gg, 256, 0, stream>>>(Ag, Wb, out, M);

    proj2_kernel<<<(M + 3) / 4, 256, 0, stream>>>(Ag, wproj, outp, M);
}

// Round 3
// 397.634 us; speedup vs baseline: 1.0271x; 1.0271x over previous
//
#include <hip/hip_runtime.h>
#include <hip/hip_bf16.h>
#include <math.h>

// Problem constants (from reference)
#define PTOK 4096      // P
#define BDIM 4         // B
#define FULLD 4096     // FULL
#define SLICE 512
#define SL_START 1024
#define EDIM 1024
#define FP_MIN_C 0.1875f
#define FP_MAX_C 0.4375f

typedef __attribute__((ext_vector_type(8))) short bf16x8;
typedef __attribute__((ext_vector_type(4))) float f32x4;

// round-to-nearest-even f32 -> bf16 bits
__device__ __forceinline__ unsigned short f2bf(float f) {
    unsigned int u = __float_as_uint(f);
    unsigned int r = (u + 0x7fffu + ((u >> 16) & 1u)) >> 16;
    return (unsigned short)r;
}

__device__ __forceinline__ void gl2lds16(const void* g, void* l) {
    __builtin_amdgcn_global_load_lds(
        (const __attribute__((address_space(1))) unsigned int*)g,
        (__attribute__((address_space(3))) unsigned int*)(unsigned long long)(uintptr_t)l,
        16, 0, 0);
}

// ---------------------------------------------------------------------------
// 1) fused prep (round-0 structure + appended wproj blocks):
//    block 0        = fingerprint scan
//    blocks 1..5    = dirs normalize (kept for minimal diff vs proven binary)
//    blocks 6..389  = weight fp32->bf16 convert
//    blocks 390..401= wproj[z,v,k] = sum_d norm(penta)[v,d] * W_z[d,k]
//                     (12 blocks: z x 128-col quarter, 8-way d-split so the
//                      per-thread global-load chain is only 128 deep)
// ---------------------------------------------------------------------------
__global__ __launch_bounds__(1024) void prep_kernel(const float* __restrict__ fp,
                                                    int* __restrict__ idx,
                                                    const float* __restrict__ penta,
                                                    float* __restrict__ dirs,
                                                    const float* __restrict__ Wq,
                                                    const float* __restrict__ Wk,
                                                    const float* __restrict__ Wv,
                                                    unsigned short* __restrict__ Wb,
                                                    float* __restrict__ wproj) {
    int blk = blockIdx.x;
    int t = threadIdx.x;
    if (blk == 0) {
        // shuffle-based scan over 4096 fingerprints (4/thread)
        int m[4];
        int c = 0;
#pragma unroll
        for (int i = 0; i < 4; ++i) {
            float f = fp[t * 4 + i];
            m[i] = (f >= FP_MIN_C && f < FP_MAX_C) ? 1 : 0;
            c += m[i];
        }
        int lane = t & 63, wv = t >> 6;
        int inc = c;
#pragma unroll
        for (int off = 1; off < 64; off <<= 1) {
            int n = __shfl_up(inc, off, 64);
            if (lane >= off) inc += n;
        }
        __shared__ int wsum[16];
        if (lane == 63) wsum[wv] = inc;
        __syncthreads();
        if (t < 16) {
            int v = wsum[t];
            int in2 = v;
#pragma unroll
            for (int off = 1; off < 16; off <<= 1) {
                int n = __shfl_up(in2, off, 16);
                if (t >= off) in2 += n;
            }
            wsum[t] = in2 - v;  // exclusive wave base
        }
        __syncthreads();
        int pos = wsum[wv] + inc - c;
#pragma unroll
        for (int i = 0; i < 4; ++i) {
            if (m[i]) idx[pos++] = t * 4 + i;
        }
    } else if (blk <= 5) {
        int v = blk - 1;
        float4 p = make_float4(0.f, 0.f, 0.f, 0.f);
        float ss = 0.f;
        if (t < 256) {
            p = ((const float4*)(penta + (size_t)v * EDIM))[t];
            ss = p.x * p.x + p.y * p.y + p.z * p.z + p.w * p.w;
        }
        for (int off = 32; off > 0; off >>= 1) ss += __shfl_down(ss, off, 64);
        __shared__ float dsum[16];
        if ((t & 63) == 0) dsum[t >> 6] = ss;
        __syncthreads();
        if (t < 256) {
            float tot = dsum[0] + dsum[1] + dsum[2] + dsum[3];
            float inv = 1.0f / sqrtf(tot);
            float4 o = make_float4(p.x * inv, p.y * inv, p.z * inv, p.w * inv);
            ((float4*)(dirs + (size_t)v * EDIM))[t] = o;
        }
    } else if (blk < 390) {
        int i = (blk - 6) * 1024 + t;  // float4 index over 3*131072
        int mat = i >> 17;
        int rem = i & 131071;
        const float* src = (mat == 0) ? Wq : ((mat == 1) ? Wk : Wv);
        float4 v = ((const float4*)src)[rem];
        ushort4 o;
        o.x = f2bf(v.x); o.y = f2bf(v.y); o.z = f2bf(v.z); o.w = f2bf(v.w);
        ((ushort4*)(Wb + (size_t)mat * EDIM * SLICE))[rem] = o;
    } else {
        // wproj: q = 0..11 -> matrix zz (0..2), column-quarter kq (0..3)
        int q = blk - 390;
        int zz = q >> 2;
        int kq = q & 3;
        __shared__ float dl[5 * EDIM + 8];  // penta rows; reused for partials
        for (int i = t; i < 5 * EDIM; i += 1024) dl[i] = penta[i];
        __syncthreads();
        if (t < 320) {  // 5 waves: inverse norms
            int v = t >> 6, l = t & 63;
            float ss = 0.f;
            for (int i = l; i < EDIM; i += 64) {
                float x = dl[v * EDIM + i];
                ss += x * x;
            }
            for (int off = 32; off > 0; off >>= 1) ss += __shfl_down(ss, off, 64);
            if (l == 0) dl[5 * EDIM + v] = 1.0f / sqrtf(ss);
        }
        __syncthreads();
        int kk = t & 127;      // column within quarter
        int dg = t >> 7;       // d-group 0..7 (128 d each)
        int k = kq * 128 + kk;
        const float* Wz = (zz == 0) ? Wq : ((zz == 1) ? Wk : Wv);
        float acc[5] = {0.f, 0.f, 0.f, 0.f, 0.f};
#pragma unroll 4
        for (int d0 = 0; d0 < 128; ++d0) {
            int d = dg * 128 + d0;
            float w = Wz[(size_t)d * SLICE + k];
#pragma unroll
            for (int v = 0; v < 5; ++v) acc[v] += w * dl[v * EDIM + d];
        }
        __syncthreads();  // done reading penta region before overwrite
#pragma unroll
        for (int v = 0; v < 5; ++v) dl[(dg * 5 + v) * 128 + kk] = acc[v];
        __syncthreads();
        if (t < 128) {
#pragma unroll
            for (int v = 0; v < 5; ++v) {
                float s = 0.f;
#pragma unroll
                for (int g = 0; g < 8; ++g) s += dl[(g * 5 + v) * 128 + t];
                float inv = dl[5 * EDIM + v];
                wproj[((size_t)zz * 5 + v) * SLICE + kq * 128 + t] = s * inv;
            }
        }
    }
}

// ---------------------------------------------------------------------------
// 2) gather + gating MLP + scale -> Ag (M x 512, bf16); 8 tokens per block
// ---------------------------------------------------------------------------
#define GT 8
__global__ __launch_bounds__(256) void gate_kernel(const float* __restrict__ tokens,
                                                   const int* __restrict__ idx,
                                                   const float* __restrict__ Wg1,
                                                   const float* __restrict__ bg1,
                                                   const float* __restrict__ Wg2,
                                                   const float* __restrict__ bg2,
                                                   const float* __restrict__ alpha,
                                                   unsigned short* __restrict__ Ag,
                                                   int Ntok, int M) {
    __shared__ float rows[GT][SLICE];   // 16 KB
    __shared__ float hred[GT][128];     // 4 KB
    __shared__ float ssc[GT];

    int tid = threadIdx.x;
    int tok0 = blockIdx.x * GT;

    // stage 8 token rows (coalesced within each half-row)
#pragma unroll
    for (int i = 0; i < 4; ++i) {
        int flat = i * 256 + tid;           // float4 slot
        int tk = flat >> 7, c4 = flat & 127;
        int g = tok0 + tk;
        if (g >= M) g = M - 1;
        int b = g / Ntok;
        int j = g - b * Ntok;
        int p = idx[j];
        const float4* src = (const float4*)(tokens + ((size_t)b * PTOK + p) * FULLD + SL_START);
        ((float4*)rows[tk])[c4] = src[c4];
    }
    __syncthreads();

    int hidx = tid & 127;
    int grp = tid >> 7;  // tokens grp*4 .. grp*4+3
    const float4* w4 = (const float4*)(Wg1 + (size_t)hidx * SLICE);
    float bias = bg1[hidx];
    float acc[4] = {bias, bias, bias, bias};
#pragma unroll 4
    for (int k = 0; k < SLICE / 4; ++k) {
        float4 w = w4[k];
#pragma unroll
        for (int t8 = 0; t8 < 4; ++t8) {
            float4 r = ((const float4*)rows[grp * 4 + t8])[k];
            acc[t8] += r.x * w.x + r.y * w.y + r.z * w.z + r.w * w.w;
        }
    }
    float wg2 = Wg2[hidx];
#pragma unroll
    for (int t8 = 0; t8 < 4; ++t8) {
        float a = acc[t8];
        float hg = 0.5f * a * (1.0f + erff(a * 0.70710678118654752f));
        hred[grp * 4 + t8][hidx] = hg * wg2;
    }
    __syncthreads();

    int wv = tid >> 6, l = tid & 63;
    float aw = 1.0f / (1.0f + expf(-alpha[0]));
#pragma unroll
    for (int z = 0; z < 2; ++z) {
        int tk = wv * 2 + z;
        float v = hred[tk][l] + hred[tk][l + 64];
        for (int off = 32; off > 0; off >>= 1) v += __shfl_down(v, off, 64);
        if (l == 0) {
            float logit = v + bg2[0];
            float gate = 1.0f / (1.0f + expf(-logit));
            ssc[tk] = gate * aw + (1.0f - aw);
        }
    }
    __syncthreads();

#pragma unroll
    for (int i = 0; i < 4; ++i) {
        int flat = i * 256 + tid;
        int tk = flat >> 7, c4 = flat & 127;
        int g = tok0 + tk;
        if (g < M) {
            float4 r = ((const float4*)rows[tk])[c4];
            float s = ssc[tk];
            ushort4 o;
            o.x = f2bf(r.x * s); o.y = f2bf(r.y * s);
            o.z = f2bf(r.z * s); o.w = f2bf(r.w * s);
            ((ushort4*)(Ag + (size_t)g * SLICE))[c4] = o;
        }
    }
}

// ---------------------------------------------------------------------------
// 3) MFMA bf16 GEMM: C[m,n] = sum_k A[m,k] * W[n,k]
//    128x128 tile, BK=64 as two 32-col panels (keeps global_load_lds lane
//    contiguity AND conflict-free 32-col ds_read layout), 16 barriers total.
//    (byte-identical to the twice-measured 387.x version)
// ---------------------------------------------------------------------------
__global__ __launch_bounds__(256) void qkv_mfma(const unsigned short* __restrict__ Ag,
                                                const unsigned short* __restrict__ Wb,
                                                float* __restrict__ out, int M) {
    __shared__ short As[2][128 * 32];
    __shared__ short Bs[2][128 * 32];

    const unsigned short* W = Wb + (size_t)blockIdx.z * EDIM * SLICE;
    float* C = out + (size_t)blockIdx.z * M * EDIM;

    int tid = threadIdx.x;
    int bm = blockIdx.y * 128;
    int bn = blockIdx.x * 128;
    int l = tid & 63;
    int w = tid >> 6;
    int wr = w >> 1, wc = w & 1;  // 2x2 wave grid
    int lane16 = l & 15, kq = l >> 4;

    int srow = tid >> 2;
    int scol = (tid & 3) * 8;

    f32x4 acc[4][4] = {};

    for (int k0 = 0; k0 < SLICE; k0 += 64) {
#pragma unroll
        for (int p = 0; p < 2; ++p) {
#pragma unroll
            for (int r = 0; r < 2; ++r) {
                int arow = bm + r * 64 + srow;
                if (arow >= M) arow = M - 1;  // clamp (stores are guarded)
                gl2lds16(Ag + (size_t)arow * SLICE + k0 + p * 32 + scol,
                         &As[p][(r * 64 + srow) * 32 + scol]);
                int brow = bn + r * 64 + srow;
                gl2lds16(W + (size_t)brow * SLICE + k0 + p * 32 + scol,
                         &Bs[p][(r * 64 + srow) * 32 + scol]);
            }
        }
        __syncthreads();

#pragma unroll
        for (int p = 0; p < 2; ++p) {
            bf16x8 a[4], b[4];
#pragma unroll
            for (int i = 0; i < 4; ++i)
                a[i] = *(const bf16x8*)&As[p][(wr * 64 + i * 16 + lane16) * 32 + kq * 8];
#pragma unroll
            for (int j = 0; j < 4; ++j)
                b[j] = *(const bf16x8*)&Bs[p][(wc * 64 + j * 16 + lane16) * 32 + kq * 8];
#pragma unroll
            for (int i = 0; i < 4; ++i)
#pragma unroll
                for (int j = 0; j < 4; ++j)
                    acc[i][j] = __builtin_amdgcn_mfma_f32_16x16x32_bf16(a[i], b[j], acc[i][j], 0, 0, 0);
        }
        __syncthreads();
    }

    // D mapping: row m = (l>>4)*4 + reg, col n = l&15
#pragma unroll
    for (int i = 0; i < 4; ++i) {
        int m0 = bm + wr * 64 + i * 16 + kq * 4;
#pragma unroll
        for (int j = 0; j < 4; ++j) {
            int n = bn + wc * 64 + j * 16 + lane16;
            f32x4 v = acc[i][j];
#pragma unroll
            for (int r = 0; r < 4; ++r) {
                int m = m0 + r;
                if (m < M) C[(size_t)m * EDIM + n] = v[r];
            }
        }
    }
}

// ---------------------------------------------------------------------------
// 4) pentachoron projections via precomposed Wproj: reads Ag (4 MB bf16)
//    instead of Q/K/V (50 MB f32). Wave per token row, 15 outputs/row.
// ---------------------------------------------------------------------------
__global__ __launch_bounds__(256) void proj2_kernel(const unsigned short* __restrict__ Ag,
                                                    const float* __restrict__ wproj,
                                                    float* __restrict__ outp, int M) {
    int t = threadIdx.x;
    int m = blockIdx.x * 4 + (t >> 6);
    if (m >= M) return;
    int l = t & 63;

    // lane l holds a[8l..8l+7] of the scaled-gated row, as f32
    bf16x8 av = *(const bf16x8*)(Ag + (size_t)m * SLICE + (size_t)l * 8);
    float a[8];
#pragma unroll
    for (int i = 0; i < 8; ++i)
        a[i] = __uint_as_float(((unsigned int)(unsigned short)av[i]) << 16);

#pragma unroll
    for (int v = 0; v < 15; ++v) {
        const float4* wp4 = (const float4*)(wproj + (size_t)v * SLICE);
        float4 w0 = wp4[l * 2];
        float4 w1 = wp4[l * 2 + 1];
        float s = a[0] * w0.x + a[1] * w0.y + a[2] * w0.z + a[3] * w0.w
                + a[4] * w1.x + a[5] * w1.y + a[6] * w1.z + a[7] * w1.w;
#pragma unroll
        for (int off = 32; off > 0; off >>= 1) s += __shfl_down(s, off, 64);
        if (l == 0) outp[(size_t)v * M + m] = s;
    }
}

// ---------------------------------------------------------------------------
extern "C" void kernel_launch(void* const* d_in, const int* in_sizes, int n_in,
                              void* d_out, int out_size, void* d_ws, size_t ws_size,
                              hipStream_t stream) {
    const float* tokens = (const float*)d_in[0];
    const float* fp     = (const float*)d_in[1];
    const float* Wg1    = (const float*)d_in[2];
    const float* bg1    = (const float*)d_in[3];
    const float* Wg2    = (const float*)d_in[4];
    const float* bg2    = (const float*)d_in[5];
    const float* alpha  = (const float*)d_in[6];
    const float* Wq     = (const float*)d_in[7];
    const float* Wk     = (const float*)d_in[8];
    const float* Wv     = (const float*)d_in[9];
    const float* penta  = (const float*)d_in[10];
    float* out = (float*)d_out;

    int Ntok = out_size / 12348;
    int M = BDIM * Ntok;

    char* ws = (char*)d_ws;
    int*            idx   = (int*)ws;
    unsigned short* Ag    = (unsigned short*)(ws + (32 << 10));
    unsigned short* Wb    = (unsigned short*)(ws + (8 << 20));
    float*          dirs  = (float*)(ws + (12 << 20));
    float*          wproj = (float*)(ws + (13 << 20));  // 15 x 512 f32

    float* outp = out + (size_t)3 * M * EDIM;  // projection region (15*M floats)

    prep_kernel<<<402, 1024, 0, stream>>>(fp, idx, penta, dirs, Wq, Wk, Wv, Wb, wproj);
    gate_kernel<<<(M + GT - 1) / GT, 256, 0, stream>>>(tokens, idx, Wg1, bg1, Wg2, bg2,
                                                       alpha, Ag, Ntok, M);

    dim3 gg(EDIM / 128, (M + 127) / 128, 3);
    qkv_mfma<<<gg, 256, 0, stream>>>(Ag, Wb, out, M);

    proj2_kernel<<<(M + 3) / 4, 256, 0, stream>>>(Ag, wproj, outp, M);
}